// Round 1
// baseline (251.414 us; speedup 1.0000x reference)
//
#include <hip/hip_runtime.h>

#define DIM     128
#define NCODES  1024
#define TILE_M  64
#define LDSS    136          // 128 + 8 halves pad: row stride 272 B -> b128 bank-group advance 17 (odd)
#define DELTA   0.02f        // screening gap; Hoeffding-safe vs fp16 rounding error

typedef __attribute__((ext_vector_type(8))) _Float16 half8;
typedef __attribute__((ext_vector_type(4))) _Float16 half4;
typedef __attribute__((ext_vector_type(4))) float    f32x4;

// ws layout:
//      0 : e2d  (1024 double)  8 KB
//   8192 : e2f  (1024 float)   4 KB
//  12288 : eh   (1024*128 _Float16) 256 KB
// 274432 : cnt  (int)
// 274436 : list (65536 int)

// -------- prep: e2 in f32+f64, fp16 codebook copy, zero flag counter --------
__global__ __launch_bounds__(256) void prep_kernel(
    const float* __restrict__ embed, double* __restrict__ e2d,
    float* __restrict__ e2f, _Float16* __restrict__ eh, int* __restrict__ cnt)
{
  if (blockIdx.x == 0 && threadIdx.x == 0) *cnt = 0;
  const int w = threadIdx.x >> 6;
  const int l = threadIdx.x & 63;
  const int c = blockIdx.x * 4 + w;            // grid = 256 blocks -> 1024 codes
  const float* row = embed + (size_t)c * DIM;
  float v0 = row[l], v1 = row[l + 64];
  eh[(size_t)c * DIM + l]      = (_Float16)v0;
  eh[(size_t)c * DIM + 64 + l] = (_Float16)v1;
  double sq = (double)v0 * v0 + (double)v1 * v1;
  #pragma unroll
  for (int off = 32; off >= 1; off >>= 1) sq += __shfl_down(sq, off, 64);
  if (l == 0) { e2d[c] = sq; e2f[c] = (float)sq; }
}

// -------- pass1: fp16 MFMA screening + top-2 argmin + gather ---------------
__global__ __launch_bounds__(256, 2) void pass1_kernel(
    const float* __restrict__ x, const float* __restrict__ embed,
    const _Float16* __restrict__ eh, const float* __restrict__ e2f,
    float* __restrict__ outQ, float* __restrict__ outIdx,
    int* __restrict__ cnt, int* __restrict__ list)
{
  __shared__ _Float16 xh[TILE_M * LDSS];
  __shared__ float rb_best[4][TILE_M];
  __shared__ float rb_sec [4][TILE_M];
  __shared__ int   rb_idx [4][TILE_M];
  __shared__ int   fidx[TILE_M];

  const int tid  = threadIdx.x;
  const int row0 = blockIdx.x * TILE_M;

  // stage x tile (64x128 f32 -> fp16 LDS, padded stride)
  {
    const f32x4* x4 = (const f32x4*)(x + (size_t)row0 * DIM);
    #pragma unroll
    for (int i = 0; i < 8; ++i) {
      int e = tid + i * 256;                 // 2048 float4s
      int r = e >> 5, c4 = e & 31;
      f32x4 v = x4[e];
      half4 h;
      h[0] = (_Float16)v[0]; h[1] = (_Float16)v[1];
      h[2] = (_Float16)v[2]; h[3] = (_Float16)v[3];
      *(half4*)&xh[r * LDSS + c4 * 4] = h;
    }
  }
  __syncthreads();

  const int l  = tid & 63, w = tid >> 6;
  const int rl = l & 15,  q = l >> 4;
  const int col0 = q * 8;

  // preload ALL A fragments: 4 m-subs x 4 k-steps (reused for 256 codes)
  half8 afrag[4][4];
  #pragma unroll
  for (int m = 0; m < 4; ++m)
    #pragma unroll
    for (int ks = 0; ks < 4; ++ks)
      afrag[m][ks] = *(const half8*)&xh[(m * 16 + rl) * LDSS + ks * 32 + col0];

  float bestv[16], secv[16]; int besti[16];
  #pragma unroll
  for (int s = 0; s < 16; ++s) { bestv[s] = 3.4e38f; secv[s] = 3.4e38f; besti[s] = 0; }

  const int codeBase = w * 256;              // wave-private code range

  // register double-buffer of B fragments (global fp16, L2-resident)
  half8 bcur[4], bnxt[4];
  {
    const half8* bb = (const half8*)(eh + (size_t)(codeBase + rl) * DIM + col0);
    #pragma unroll
    for (int ks = 0; ks < 4; ++ks) bcur[ks] = bb[ks * 4];
  }
  float e2cur = e2f[codeBase + rl];

  for (int ch = 0; ch < 16; ++ch) {
    const int mycode = codeBase + ch * 16 + rl;
    if (ch < 15) {
      const half8* bb = (const half8*)(eh + (size_t)(mycode + 16) * DIM + col0);
      #pragma unroll
      for (int ks = 0; ks < 4; ++ks) bnxt[ks] = bb[ks * 4];
    }
    float e2nxt = (ch < 15) ? e2f[mycode + 16] : 0.f;

    f32x4 acc[4];
    #pragma unroll
    for (int m = 0; m < 4; ++m) acc[m] = (f32x4){0.f, 0.f, 0.f, 0.f};
    #pragma unroll
    for (int ks = 0; ks < 4; ++ks)
      #pragma unroll
      for (int m = 0; m < 4; ++m)
        acc[m] = __builtin_amdgcn_mfma_f32_16x16x32_f16(afrag[m][ks], bcur[ks], acc[m], 0, 0, 0);

    // top-2 tracking: slot (m,r) = x-row m*16+q*4+r, code column = mycode
    #pragma unroll
    for (int m = 0; m < 4; ++m)
      #pragma unroll
      for (int r = 0; r < 4; ++r) {
        const int s = m * 4 + r;
        float sc = fmaf(-2.0f, acc[m][r], e2cur);
        bool better = sc < bestv[s];
        float old   = bestv[s];
        bestv[s] = better ? sc : bestv[s];
        besti[s] = better ? mycode : besti[s];
        float cand = better ? old : sc;
        secv[s] = cand < secv[s] ? cand : secv[s];
      }

    #pragma unroll
    for (int ks = 0; ks < 4; ++ks) bcur[ks] = bnxt[ks];
    e2cur = e2nxt;
  }

  // merge across the 16 lanes of each quarter (same rows, different codes)
  #pragma unroll
  for (int off = 1; off < 16; off <<= 1) {
    #pragma unroll
    for (int s = 0; s < 16; ++s) {
      float ob = __shfl_xor(bestv[s], off, 16);
      float os = __shfl_xor(secv[s],  off, 16);
      int   oi = __shfl_xor(besti[s], off, 16);
      bool take = (ob < bestv[s]) || (ob == bestv[s] && oi < besti[s]);
      float loser = take ? bestv[s] : ob;
      bestv[s] = take ? ob : bestv[s];
      besti[s] = take ? oi : besti[s];
      float m2 = os < loser ? os : loser;
      secv[s] = secv[s] < m2 ? secv[s] : m2;
    }
  }
  if (rl == 0) {
    #pragma unroll
    for (int m = 0; m < 4; ++m)
      #pragma unroll
      for (int r = 0; r < 4; ++r) {
        int s = m * 4 + r;
        int row = m * 16 + q * 4 + r;
        rb_best[w][row] = bestv[s];
        rb_sec [w][row] = secv[s];
        rb_idx [w][row] = besti[s];
      }
  }
  __syncthreads();

  // merge the 4 waves (disjoint code ranges), emit index + flag near-ties
  if (tid < TILE_M) {
    float bv = rb_best[0][tid], sv = rb_sec[0][tid]; int bi = rb_idx[0][tid];
    #pragma unroll
    for (int ww = 1; ww < 4; ++ww) {
      float ob = rb_best[ww][tid], os = rb_sec[ww][tid]; int oi = rb_idx[ww][tid];
      bool take = (ob < bv) || (ob == bv && oi < bi);
      float loser = take ? bv : ob;
      bv = take ? ob : bv; bi = take ? oi : bi;
      float m2 = os < loser ? os : loser;
      sv = sv < m2 ? sv : m2;
    }
    int grow = row0 + tid;
    outIdx[grow] = (float)bi;
    fidx[tid] = bi;
    if (sv - bv <= DELTA) {
      int p = atomicAdd(cnt, 1);
      list[p] = grow;
    }
  }
  __syncthreads();

  // gather quantize = embed[idx] (coalesced writes, L2-hot embed reads)
  {
    const f32x4* E4   = (const f32x4*)embed;
    f32x4*       out4 = (f32x4*)(outQ + (size_t)row0 * DIM);
    #pragma unroll
    for (int i = 0; i < 8; ++i) {
      int e = tid + i * 256;
      int r = e >> 5, c4 = e & 31;
      out4[e] = E4[fidx[r] * 32 + c4];
    }
  }
}

// -------- refine: flagged rows -> full f32 rescan, f64 top-2 decision -------
__global__ __launch_bounds__(256) void refine_kernel(
    const float* __restrict__ x, const float* __restrict__ embed,
    const double* __restrict__ e2d, const float* __restrict__ e2f,
    float* __restrict__ outQ, float* __restrict__ outIdx,
    const int* __restrict__ cnt, const int* __restrict__ list)
{
  __shared__ float xr[4][DIM];
  const int tid = threadIdx.x;
  const int l = tid & 63, w = tid >> 6;
  const int n = *cnt;
  const int nslots = gridDim.x * 4;
  const int slot = blockIdx.x * 4 + w;
  const int trips = (n + nslots - 1) / nslots;   // uniform across block

  for (int t = 0; t < trips; ++t) {
    int j = t * nslots + slot;
    bool active = j < n;
    int row = active ? list[j] : 0;
    __syncthreads();
    if (active) {
      xr[w][l]      = x[(size_t)row * DIM + l];
      xr[w][l + 64] = x[(size_t)row * DIM + 64 + l];
    }
    __syncthreads();
    if (!active) continue;   // no further barriers in body

    // full f32 scan: each lane handles 16 codes (l + 64*jj)
    float bv1 = 3.4e38f, bv2 = 3.4e38f; int bi1 = 0, bi2 = 0;
    const f32x4* xr4 = (const f32x4*)xr[w];
    #pragma unroll 2
    for (int jj = 0; jj < 16; ++jj) {
      int c = l + 64 * jj;
      const f32x4* ev = (const f32x4*)(embed + (size_t)c * DIM);
      float dot = 0.f;
      #pragma unroll
      for (int k4 = 0; k4 < 32; ++k4) {
        f32x4 e4 = ev[k4]; f32x4 x4 = xr4[k4];
        dot = fmaf(x4[0], e4[0], dot);
        dot = fmaf(x4[1], e4[1], dot);
        dot = fmaf(x4[2], e4[2], dot);
        dot = fmaf(x4[3], e4[3], dot);
      }
      float sc = fmaf(-2.f, dot, e2f[c]);
      bool better = sc < bv1;
      float o1 = bv1; int oi1 = bi1;
      bv1 = better ? sc : bv1; bi1 = better ? c : bi1;
      float cand = better ? o1 : sc; int candi = better ? oi1 : c;
      bool b2 = cand < bv2;
      bv2 = b2 ? cand : bv2; bi2 = b2 ? candi : bi2;
    }
    // wave merge of (top1, top2) with index tie-break
    #pragma unroll
    for (int off = 1; off < 64; off <<= 1) {
      float o1 = __shfl_xor(bv1, off, 64); int oi1 = __shfl_xor(bi1, off, 64);
      float o2 = __shfl_xor(bv2, off, 64); int oi2 = __shfl_xor(bi2, off, 64);
      bool take = (o1 < bv1) || (o1 == bv1 && oi1 < bi1);
      float n1 = take ? o1 : bv1; int ni1 = take ? oi1 : bi1;
      float lo = take ? bv1 : o1; int loi = take ? bi1 : oi1;
      float c2 = take ? o2 : bv2; int ci2 = take ? oi2 : bi2;
      bool t2 = (c2 < lo) || (c2 == lo && ci2 < loi);
      bv1 = n1; bi1 = ni1;
      bv2 = t2 ? c2 : lo; bi2 = t2 ? ci2 : loi;
    }
    // exact f64 rescore of the two candidates
    int c1 = bi1, c2 = bi2;
    float xa = xr[w][l], xb = xr[w][l + 64];
    double p1 = (double)xa * (double)embed[(size_t)c1 * DIM + l]
              + (double)xb * (double)embed[(size_t)c1 * DIM + 64 + l];
    double p2 = (double)xa * (double)embed[(size_t)c2 * DIM + l]
              + (double)xb * (double)embed[(size_t)c2 * DIM + 64 + l];
    #pragma unroll
    for (int off = 1; off < 64; off <<= 1) {
      p1 += __shfl_xor(p1, off, 64);
      p2 += __shfl_xor(p2, off, 64);
    }
    double s1 = e2d[c1] - 2.0 * p1;
    double s2 = e2d[c2] - 2.0 * p2;
    int widx = ((s2 < s1) || (s2 == s1 && c2 < c1)) ? c2 : c1;
    if (l == 0) outIdx[row] = (float)widx;
    outQ[(size_t)row * DIM + l]      = embed[(size_t)widx * DIM + l];
    outQ[(size_t)row * DIM + 64 + l] = embed[(size_t)widx * DIM + 64 + l];
  }
}

extern "C" void kernel_launch(void* const* d_in, const int* in_sizes, int n_in,
                              void* d_out, int out_size, void* d_ws, size_t ws_size,
                              hipStream_t stream) {
  const float* x     = (const float*)d_in[0];
  const float* embed = (const float*)d_in[1];
  const int N = in_sizes[0] / DIM;             // 65536 rows

  float* out    = (float*)d_out;
  float* outQ   = out;                         // [N*128] quantize
  float* outIdx = out + (size_t)N * DIM;       // [N] indices as float

  char* ws = (char*)d_ws;
  double*   e2d  = (double*)  (ws);
  float*    e2f  = (float*)   (ws + 8192);
  _Float16* eh   = (_Float16*)(ws + 12288);
  int*      cnt  = (int*)     (ws + 274432);
  int*      list = (int*)     (ws + 274436);

  prep_kernel  <<<NCODES / 4, 256, 0, stream>>>(embed, e2d, e2f, eh, cnt);
  pass1_kernel <<<N / TILE_M, 256, 0, stream>>>(x, embed, eh, e2f, outQ, outIdx, cnt, list);
  refine_kernel<<<256,        256, 0, stream>>>(x, embed, e2d, e2f, outQ, outIdx, cnt, list);
}

// Round 2
// 154.645 us; speedup vs baseline: 1.6258x; 1.6258x over previous
//
#include <hip/hip_runtime.h>

#define DIM     128
#define NCODES  1024
#define TILE_M  64
#define LDSS    136          // 128 + 8 halves pad
#define DELTA   0.02f        // screening gap; Hoeffding-safe vs fp16 rounding error
#define RPB     4            // refine rows per block
#define RGRID   1024         // refine grid

typedef __attribute__((ext_vector_type(8))) _Float16 half8;
typedef __attribute__((ext_vector_type(4))) _Float16 half4;
typedef __attribute__((ext_vector_type(4))) float    f32x4;

// ws layout:
//      0 : e2d    (1024 double)          8 KB
//   8192 : e2f    (1024 float)           4 KB
//  12288 : eh     (1024*128 _Float16)  256 KB
// 274432 : embedT (128*1024 float)     512 KB
// 798720 : cnt    (int)
// 798976 : list   (65536 int)          256 KB

// -------- prep: e2 in f32+f64, fp16 codebook copy, zero flag counter --------
__global__ __launch_bounds__(256) void prep_kernel(
    const float* __restrict__ embed, double* __restrict__ e2d,
    float* __restrict__ e2f, _Float16* __restrict__ eh, int* __restrict__ cnt)
{
  if (blockIdx.x == 0 && threadIdx.x == 0) *cnt = 0;
  const int w = threadIdx.x >> 6;
  const int l = threadIdx.x & 63;
  const int c = blockIdx.x * 4 + w;            // grid = 256 blocks -> 1024 codes
  const float* row = embed + (size_t)c * DIM;
  float v0 = row[l], v1 = row[l + 64];
  eh[(size_t)c * DIM + l]      = (_Float16)v0;
  eh[(size_t)c * DIM + 64 + l] = (_Float16)v1;
  double sq = (double)v0 * v0 + (double)v1 * v1;
  #pragma unroll
  for (int off = 32; off >= 1; off >>= 1) sq += __shfl_down(sq, off, 64);
  if (l == 0) { e2d[c] = sq; e2f[c] = (float)sq; }
}

// -------- transpose: embed [1024][128] -> embedT [128][1024] ---------------
__global__ __launch_bounds__(256) void transpose_kernel(
    const float* __restrict__ embed, float* __restrict__ embedT)
{
  __shared__ float tile[64][65];
  const int c0 = blockIdx.y * 64;   // code tile
  const int k0 = blockIdx.x * 64;   // dim tile
  const int t = threadIdx.x;
  #pragma unroll
  for (int i = 0; i < 16; ++i) {
    int idx = t + i * 256;
    int r = idx >> 6, c = idx & 63;      // r = code off, c = dim off
    tile[r][c] = embed[(size_t)(c0 + r) * DIM + k0 + c];
  }
  __syncthreads();
  #pragma unroll
  for (int i = 0; i < 16; ++i) {
    int idx = t + i * 256;
    int r = idx >> 6, c = idx & 63;      // r = dim off, c = code off
    embedT[(size_t)(k0 + r) * NCODES + c0 + c] = tile[c][r];
  }
}

// -------- pass1: fp16 MFMA screening + top-2 argmin + gather ---------------
__global__ __launch_bounds__(256, 2) void pass1_kernel(
    const float* __restrict__ x, const float* __restrict__ embed,
    const _Float16* __restrict__ eh, const float* __restrict__ e2f,
    float* __restrict__ outQ, float* __restrict__ outIdx,
    int* __restrict__ cnt, int* __restrict__ list)
{
  __shared__ _Float16 xh[TILE_M * LDSS];
  __shared__ float rb_best[4][TILE_M];
  __shared__ float rb_sec [4][TILE_M];
  __shared__ int   rb_idx [4][TILE_M];
  __shared__ int   fidx[TILE_M];

  const int tid  = threadIdx.x;
  const int row0 = blockIdx.x * TILE_M;

  // stage x tile (64x128 f32 -> fp16 LDS, padded stride)
  {
    const f32x4* x4 = (const f32x4*)(x + (size_t)row0 * DIM);
    #pragma unroll
    for (int i = 0; i < 8; ++i) {
      int e = tid + i * 256;                 // 2048 float4s
      int r = e >> 5, c4 = e & 31;
      f32x4 v = x4[e];
      half4 h;
      h[0] = (_Float16)v[0]; h[1] = (_Float16)v[1];
      h[2] = (_Float16)v[2]; h[3] = (_Float16)v[3];
      *(half4*)&xh[r * LDSS + c4 * 4] = h;
    }
  }
  __syncthreads();

  const int l  = tid & 63, w = tid >> 6;
  const int rl = l & 15,  q = l >> 4;
  const int col0 = q * 8;

  // preload ALL A fragments: 4 m-subs x 4 k-steps (reused for 256 codes)
  half8 afrag[4][4];
  #pragma unroll
  for (int m = 0; m < 4; ++m)
    #pragma unroll
    for (int ks = 0; ks < 4; ++ks)
      afrag[m][ks] = *(const half8*)&xh[(m * 16 + rl) * LDSS + ks * 32 + col0];

  float bestv[16], secv[16]; int besti[16];
  #pragma unroll
  for (int s = 0; s < 16; ++s) { bestv[s] = 3.4e38f; secv[s] = 3.4e38f; besti[s] = 0; }

  const int codeBase = w * 256;              // wave-private code range

  // register double-buffer of B fragments (global fp16, L2-resident)
  half8 bcur[4], bnxt[4];
  {
    const half8* bb = (const half8*)(eh + (size_t)(codeBase + rl) * DIM + col0);
    #pragma unroll
    for (int ks = 0; ks < 4; ++ks) bcur[ks] = bb[ks * 4];
  }
  float e2cur = e2f[codeBase + rl];

  for (int ch = 0; ch < 16; ++ch) {
    const int mycode = codeBase + ch * 16 + rl;
    if (ch < 15) {
      const half8* bb = (const half8*)(eh + (size_t)(mycode + 16) * DIM + col0);
      #pragma unroll
      for (int ks = 0; ks < 4; ++ks) bnxt[ks] = bb[ks * 4];
    }
    float e2nxt = (ch < 15) ? e2f[mycode + 16] : 0.f;

    f32x4 acc[4];
    #pragma unroll
    for (int m = 0; m < 4; ++m) acc[m] = (f32x4){0.f, 0.f, 0.f, 0.f};
    #pragma unroll
    for (int ks = 0; ks < 4; ++ks)
      #pragma unroll
      for (int m = 0; m < 4; ++m)
        acc[m] = __builtin_amdgcn_mfma_f32_16x16x32_f16(afrag[m][ks], bcur[ks], acc[m], 0, 0, 0);

    // top-2 tracking (exactly equivalent to cndmask form, fewer vcc deps)
    #pragma unroll
    for (int m = 0; m < 4; ++m)
      #pragma unroll
      for (int r = 0; r < 4; ++r) {
        const int s = m * 4 + r;
        float sc = fmaf(-2.0f, acc[m][r], e2cur);
        secv[s]  = fminf(secv[s], fmaxf(bestv[s], sc));
        besti[s] = (sc < bestv[s]) ? mycode : besti[s];
        bestv[s] = fminf(bestv[s], sc);
      }

    #pragma unroll
    for (int ks = 0; ks < 4; ++ks) bcur[ks] = bnxt[ks];
    e2cur = e2nxt;
  }

  // merge across the 16 lanes of each quarter (same rows, different codes)
  #pragma unroll
  for (int off = 1; off < 16; off <<= 1) {
    #pragma unroll
    for (int s = 0; s < 16; ++s) {
      float ob = __shfl_xor(bestv[s], off, 16);
      float os = __shfl_xor(secv[s],  off, 16);
      int   oi = __shfl_xor(besti[s], off, 16);
      bool take = (ob < bestv[s]) || (ob == bestv[s] && oi < besti[s]);
      float loser = take ? bestv[s] : ob;
      bestv[s] = take ? ob : bestv[s];
      besti[s] = take ? oi : besti[s];
      float m2 = os < loser ? os : loser;
      secv[s] = secv[s] < m2 ? secv[s] : m2;
    }
  }
  if (rl == 0) {
    #pragma unroll
    for (int m = 0; m < 4; ++m)
      #pragma unroll
      for (int r = 0; r < 4; ++r) {
        int s = m * 4 + r;
        int row = m * 16 + q * 4 + r;
        rb_best[w][row] = bestv[s];
        rb_sec [w][row] = secv[s];
        rb_idx [w][row] = besti[s];
      }
  }
  __syncthreads();

  // merge the 4 waves (disjoint code ranges), emit index + flag near-ties
  if (tid < TILE_M) {
    float bv = rb_best[0][tid], sv = rb_sec[0][tid]; int bi = rb_idx[0][tid];
    #pragma unroll
    for (int ww = 1; ww < 4; ++ww) {
      float ob = rb_best[ww][tid], os = rb_sec[ww][tid]; int oi = rb_idx[ww][tid];
      bool take = (ob < bv) || (ob == bv && oi < bi);
      float loser = take ? bv : ob;
      bv = take ? ob : bv; bi = take ? oi : bi;
      float m2 = os < loser ? os : loser;
      sv = sv < m2 ? sv : m2;
    }
    int grow = row0 + tid;
    outIdx[grow] = (float)bi;
    fidx[tid] = bi;
    if (sv - bv <= DELTA) {
      int p = atomicAdd(cnt, 1);
      list[p] = grow;
    }
  }
  __syncthreads();

  // gather quantize = embed[idx] (coalesced writes, L2-hot embed reads)
  {
    const f32x4* E4   = (const f32x4*)embed;
    f32x4*       out4 = (f32x4*)(outQ + (size_t)row0 * DIM);
    #pragma unroll
    for (int i = 0; i < 8; ++i) {
      int e = tid + i * 256;
      int r = e >> 5, c4 = e & 31;
      out4[e] = E4[fidx[r] * 32 + c4];
    }
  }
}

// -------- refine v2: coalesced full f32 rescan via embedT, f64 decision -----
// Bit-identical decision math to the validated v1 refine: same fmaf chain
// order (k ascending per code), canonical lexicographic (value,index) top-2,
// same f64 rescore formula and tie-break.
__global__ __launch_bounds__(256) void refine2_kernel(
    const float* __restrict__ x, const float* __restrict__ embed,
    const float* __restrict__ embedT,
    const double* __restrict__ e2d, const float* __restrict__ e2f,
    float* __restrict__ outQ, float* __restrict__ outIdx,
    const int* __restrict__ cnt, const int* __restrict__ list)
{
  __shared__ f32x4 xst[DIM];                 // xst[k][r]: k-th dim of row r
  __shared__ float rb1[RPB][4], rb2[RPB][4];
  __shared__ int   ri1[RPB][4], ri2[RPB][4];
  __shared__ int   cand[RPB][2];

  const int t = threadIdx.x;
  const int l = t & 63, w = t >> 6;
  const int n = *cnt;
  float* xsf = (float*)xst;

  for (int base = blockIdx.x * RPB; base < n; base += RGRID * RPB) {
    const int nr = min(RPB, n - base);
    // stage rows (transposed: xst[k][r])
    #pragma unroll
    for (int i = 0; i < 2; ++i) {
      int idx = t + i * 256;
      int r = idx >> 7, k = idx & 127;
      float v = 0.f;
      if (r < nr) v = x[(size_t)list[base + r] * DIM + k];
      xsf[k * RPB + r] = v;
    }
    __syncthreads();

    // thread t owns codes 4t..4t+3; fully coalesced embedT stream
    f32x4 dot[RPB];
    #pragma unroll
    for (int r = 0; r < RPB; ++r) dot[r] = (f32x4){0.f, 0.f, 0.f, 0.f};
    const f32x4* eT4 = (const f32x4*)embedT;
    #pragma unroll 4
    for (int k = 0; k < DIM; ++k) {
      f32x4 e4  = eT4[k * 256 + t];
      f32x4 xk4 = xst[k];
      #pragma unroll
      for (int r = 0; r < RPB; ++r) {
        dot[r][0] = fmaf(xk4[r], e4[0], dot[r][0]);
        dot[r][1] = fmaf(xk4[r], e4[1], dot[r][1]);
        dot[r][2] = fmaf(xk4[r], e4[2], dot[r][2]);
        dot[r][3] = fmaf(xk4[r], e4[3], dot[r][3]);
      }
    }

    // per-thread top-2 over its 4 codes, then wave + block merges
    #pragma unroll
    for (int r = 0; r < RPB; ++r) {
      float b1 = 3.4e38f, b2 = 3.4e38f; int i1 = 0, i2 = 0;
      #pragma unroll
      for (int j = 0; j < 4; ++j) {
        int c = 4 * t + j;
        float sc = fmaf(-2.0f, dot[r][j], e2f[c]);
        bool better = (sc < b1);                 // ties keep lower index
        float lv = better ? b1 : sc;  int li = better ? i1 : c;
        if (better) { b1 = sc; i1 = c; }
        bool t2 = (lv < b2) || (lv == b2 && li < i2);
        if (t2) { b2 = lv; i2 = li; }
      }
      #pragma unroll
      for (int off = 1; off < 64; off <<= 1) {
        float o1 = __shfl_xor(b1, off, 64); int oi1 = __shfl_xor(i1, off, 64);
        float o2 = __shfl_xor(b2, off, 64); int oi2 = __shfl_xor(i2, off, 64);
        bool take = (o1 < b1) || (o1 == b1 && oi1 < i1);
        float n1 = take ? o1 : b1; int ni1 = take ? oi1 : i1;
        float lo = take ? b1 : o1; int loi = take ? i1 : oi1;
        float c2v = take ? o2 : b2; int c2i = take ? oi2 : i2;
        bool u2 = (c2v < lo) || (c2v == lo && c2i < loi);
        b1 = n1; i1 = ni1;
        b2 = u2 ? c2v : lo; i2 = u2 ? c2i : loi;
      }
      if (l == 0) { rb1[r][w] = b1; ri1[r][w] = i1; rb2[r][w] = b2; ri2[r][w] = i2; }
    }
    __syncthreads();

    if (t < RPB) {
      float v1 = rb1[t][0], v2 = rb2[t][0]; int j1 = ri1[t][0], j2 = ri2[t][0];
      #pragma unroll
      for (int ww = 1; ww < 4; ++ww) {
        float o1 = rb1[t][ww], o2 = rb2[t][ww]; int oi1 = ri1[t][ww], oi2 = ri2[t][ww];
        bool take = (o1 < v1) || (o1 == v1 && oi1 < j1);
        float n1 = take ? o1 : v1; int ni1 = take ? oi1 : j1;
        float lo = take ? v1 : o1; int loi = take ? j1 : oi1;
        float c2v = take ? o2 : v2; int c2i = take ? oi2 : j2;
        bool u2 = (c2v < lo) || (c2v == lo && c2i < loi);
        v1 = n1; j1 = ni1; v2 = u2 ? c2v : lo; j2 = u2 ? c2i : loi;
      }
      cand[t][0] = j1; cand[t][1] = j2;
    }
    __syncthreads();

    // f64 rescore of the two candidates: wave w handles row w
    if (w < nr) {
      int c1 = cand[w][0], c2 = cand[w][1];
      float xa = xsf[l * RPB + w], xb = xsf[(l + 64) * RPB + w];
      double p1 = (double)xa * (double)embed[(size_t)c1 * DIM + l]
                + (double)xb * (double)embed[(size_t)c1 * DIM + 64 + l];
      double p2 = (double)xa * (double)embed[(size_t)c2 * DIM + l]
                + (double)xb * (double)embed[(size_t)c2 * DIM + 64 + l];
      #pragma unroll
      for (int off = 1; off < 64; off <<= 1) {
        p1 += __shfl_xor(p1, off, 64);
        p2 += __shfl_xor(p2, off, 64);
      }
      double s1 = e2d[c1] - 2.0 * p1;
      double s2 = e2d[c2] - 2.0 * p2;
      int widx = ((s2 < s1) || (s2 == s1 && c2 < c1)) ? c2 : c1;
      int row = list[base + w];
      if (l == 0) outIdx[row] = (float)widx;
      outQ[(size_t)row * DIM + l]      = embed[(size_t)widx * DIM + l];
      outQ[(size_t)row * DIM + 64 + l] = embed[(size_t)widx * DIM + 64 + l];
    }
    __syncthreads();   // xst reused next trip
  }
}

extern "C" void kernel_launch(void* const* d_in, const int* in_sizes, int n_in,
                              void* d_out, int out_size, void* d_ws, size_t ws_size,
                              hipStream_t stream) {
  const float* x     = (const float*)d_in[0];
  const float* embed = (const float*)d_in[1];
  const int N = in_sizes[0] / DIM;             // 65536 rows

  float* out    = (float*)d_out;
  float* outQ   = out;                         // [N*128] quantize
  float* outIdx = out + (size_t)N * DIM;       // [N] indices as float

  char* ws = (char*)d_ws;
  double*   e2d  = (double*)  (ws);
  float*    e2f  = (float*)   (ws + 8192);
  _Float16* eh   = (_Float16*)(ws + 12288);
  float*    eT   = (float*)   (ws + 274432);
  int*      cnt  = (int*)     (ws + 798720);
  int*      list = (int*)     (ws + 798976);

  prep_kernel     <<<NCODES / 4, 256, 0, stream>>>(embed, e2d, e2f, eh, cnt);
  dim3 tg(DIM / 64, NCODES / 64);
  transpose_kernel<<<tg,         256, 0, stream>>>(embed, eT);
  pass1_kernel    <<<N / TILE_M, 256, 0, stream>>>(x, embed, eh, e2f, outQ, outIdx, cnt, list);
  refine2_kernel  <<<RGRID,      256, 0, stream>>>(x, embed, eT, e2d, e2f, outQ, outIdx, cnt, list);
}

// Round 3
// 141.506 us; speedup vs baseline: 1.7767x; 1.0928x over previous
//
#include <hip/hip_runtime.h>

#define DIM     128
#define NCODES  1024
#define TILE_M  64
#define LDSS    136          // 128 + 8 halves pad: row stride 272 B = 17 x 16 B (2-way, free)
#define DELTA   0.02f        // screening gap; Hoeffding-safe vs fp16 rounding error
#define RPB     4            // refine rows per block
#define RGRID   1024         // refine grid

typedef __attribute__((ext_vector_type(8))) _Float16 half8;
typedef __attribute__((ext_vector_type(4))) _Float16 half4;
typedef __attribute__((ext_vector_type(4))) float    f32x4;

// ws layout:
//      0 : e2d    (1024 double)          8 KB
//   8192 : e2f    (1024 float)           4 KB
//  12288 : eh     (1024*128 _Float16)  256 KB
// 274432 : embedT (128*1024 float)     512 KB
// 798720 : cnt    (int)
// 798976 : list   (65536 int)          256 KB

// -------- prep: e2 in f32+f64, fp16 codebook copy, zero flag counter --------
__global__ __launch_bounds__(256) void prep_kernel(
    const float* __restrict__ embed, double* __restrict__ e2d,
    float* __restrict__ e2f, _Float16* __restrict__ eh, int* __restrict__ cnt)
{
  if (blockIdx.x == 0 && threadIdx.x == 0) *cnt = 0;
  const int w = threadIdx.x >> 6;
  const int l = threadIdx.x & 63;
  const int c = blockIdx.x * 4 + w;            // grid = 256 blocks -> 1024 codes
  const float* row = embed + (size_t)c * DIM;
  float v0 = row[l], v1 = row[l + 64];
  eh[(size_t)c * DIM + l]      = (_Float16)v0;
  eh[(size_t)c * DIM + 64 + l] = (_Float16)v1;
  double sq = (double)v0 * v0 + (double)v1 * v1;
  #pragma unroll
  for (int off = 32; off >= 1; off >>= 1) sq += __shfl_down(sq, off, 64);
  if (l == 0) { e2d[c] = sq; e2f[c] = (float)sq; }
}

// -------- transpose: embed [1024][128] -> embedT [128][1024] ---------------
__global__ __launch_bounds__(256) void transpose_kernel(
    const float* __restrict__ embed, float* __restrict__ embedT)
{
  __shared__ float tile[64][65];
  const int c0 = blockIdx.y * 64;   // code tile
  const int k0 = blockIdx.x * 64;   // dim tile
  const int t = threadIdx.x;
  #pragma unroll
  for (int i = 0; i < 16; ++i) {
    int idx = t + i * 256;
    int r = idx >> 6, c = idx & 63;      // r = code off, c = dim off
    tile[r][c] = embed[(size_t)(c0 + r) * DIM + k0 + c];
  }
  __syncthreads();
  #pragma unroll
  for (int i = 0; i < 16; ++i) {
    int idx = t + i * 256;
    int r = idx >> 6, c = idx & 63;      // r = dim off, c = code off
    embedT[(size_t)(k0 + r) * NCODES + c0 + c] = tile[c][r];
  }
}

// -------- pass1 v3: fp16 MFMA screening, packed-index top-2, lean regs -----
// Index packed into low 10 mantissa bits of the score; pack error <= |v|*2^-13,
// covered by the adaptive flag pad |best|*2^-11. All rows with top-2 gap <=
// DELTA(+pad) are re-decided exactly by refine2 (independent full rescan).
__global__ __launch_bounds__(256)
__attribute__((amdgpu_waves_per_eu(4, 4)))
void pass1_kernel(
    const float* __restrict__ x, const float* __restrict__ embed,
    const _Float16* __restrict__ eh, const float* __restrict__ e2f,
    float* __restrict__ outQ, float* __restrict__ outIdx,
    int* __restrict__ cnt, int* __restrict__ list)
{
  __shared__ _Float16 xh[TILE_M * LDSS];
  __shared__ float rb_best[4][TILE_M];
  __shared__ float rb_sec [4][TILE_M];
  __shared__ int   fidx[TILE_M];

  const int tid  = threadIdx.x;
  const int row0 = blockIdx.x * TILE_M;

  // stage x tile (64x128 f32 -> fp16 LDS, padded stride)
  {
    const f32x4* x4 = (const f32x4*)(x + (size_t)row0 * DIM);
    #pragma unroll
    for (int i = 0; i < 8; ++i) {
      int e = tid + i * 256;                 // 2048 float4s
      int r = e >> 5, c4 = e & 31;
      f32x4 v = x4[e];
      half4 h;
      h[0] = (_Float16)v[0]; h[1] = (_Float16)v[1];
      h[2] = (_Float16)v[2]; h[3] = (_Float16)v[3];
      *(half4*)&xh[r * LDSS + c4 * 4] = h;
    }
  }
  __syncthreads();

  const int l  = tid & 63, w = tid >> 6;
  const int rl = l & 15,  q = l >> 4;
  const int col0 = q * 8;
  const int abase0 = rl * LDSS + col0;       // A-fragment base (halves)

  float bestp[16], secp[16];
  #pragma unroll
  for (int s = 0; s < 16; ++s) { bestp[s] = 3.0e38f; secp[s] = 3.3e38f; }

  const int codeBase = w * 256;              // wave-private code range
  const _Float16* ehw = eh + (size_t)(codeBase + rl) * DIM + col0;

  // B register double-buffer (global fp16, L2-resident)
  half8 bbuf[2][4];
  float e2buf[2];
  #pragma unroll
  for (int ks = 0; ks < 4; ++ks) bbuf[0][ks] = *(const half8*)(ehw + ks * 32);
  e2buf[0] = e2f[codeBase + rl];

  #pragma unroll 2
  for (int ch = 0; ch < 16; ++ch) {
    const int cur = ch & 1, nxt = cur ^ 1;
    const int mycode = codeBase + ch * 16 + rl;
    if (ch < 15) {
      const _Float16* ehn = ehw + (size_t)(ch + 1) * (16 * DIM);
      #pragma unroll
      for (int ks = 0; ks < 4; ++ks) bbuf[nxt][ks] = *(const half8*)(ehn + ks * 32);
      e2buf[nxt] = e2f[mycode + 16];
    }
    const float e2c = e2buf[cur];

    // opaque zero: blocks LICM from hoisting the A ds_reads into registers
    int ozero = 0;
    asm volatile("" : "+v"(ozero));
    const int ab = abase0 + ozero;

    #pragma unroll
    for (int m = 0; m < 4; ++m) {
      f32x4 acc = (f32x4){0.f, 0.f, 0.f, 0.f};
      #pragma unroll
      for (int ks = 0; ks < 4; ++ks) {
        half8 af = *(const half8*)&xh[ab + m * (16 * LDSS) + ks * 32];
        acc = __builtin_amdgcn_mfma_f32_16x16x32_f16(af, bbuf[cur][ks], acc, 0, 0, 0);
      }
      #pragma unroll
      for (int r = 0; r < 4; ++r) {
        const int s = m * 4 + r;
        float sc  = fmaf(-2.0f, acc[r], e2c);
        float scp = __int_as_float((__float_as_int(sc) & ~1023) | mycode);
        secp[s]  = fminf(secp[s], fmaxf(bestp[s], scp));
        bestp[s] = fminf(bestp[s], scp);
      }
    }
  }

  // merge across the 16 lanes of each quarter (same rows, different codes)
  #pragma unroll
  for (int off = 1; off < 16; off <<= 1) {
    #pragma unroll
    for (int s = 0; s < 16; ++s) {
      float ob = __shfl_xor(bestp[s], off, 16);
      float os = __shfl_xor(secp[s],  off, 16);
      float mx = fmaxf(bestp[s], ob);
      bestp[s] = fminf(bestp[s], ob);
      secp[s]  = fminf(fminf(secp[s], os), mx);
    }
  }
  if (rl == 0) {
    #pragma unroll
    for (int m = 0; m < 4; ++m)
      #pragma unroll
      for (int r = 0; r < 4; ++r) {
        int s = m * 4 + r;
        int row = m * 16 + q * 4 + r;
        rb_best[w][row] = bestp[s];
        rb_sec [w][row] = secp[s];
      }
  }
  __syncthreads();

  // merge the 4 waves (disjoint code ranges), emit index + flag near-ties
  if (tid < TILE_M) {
    float bv = rb_best[0][tid], sv = rb_sec[0][tid];
    #pragma unroll
    for (int ww = 1; ww < 4; ++ww) {
      float ob = rb_best[ww][tid], os = rb_sec[ww][tid];
      float mx = fmaxf(bv, ob);
      bv = fminf(bv, ob);
      sv = fminf(fminf(sv, os), mx);
    }
    int bi = __float_as_int(bv) & 1023;
    int grow = row0 + tid;
    outIdx[grow] = (float)bi;
    fidx[tid] = bi;
    // adaptive pad covers packed-index perturbation of bv and sv
    if (sv - bv <= DELTA + fabsf(bv) * 4.8828125e-4f) {
      int p = atomicAdd(cnt, 1);
      list[p] = grow;
    }
  }
  __syncthreads();

  // gather quantize = embed[idx] (coalesced writes, L2-hot embed reads)
  {
    const f32x4* E4   = (const f32x4*)embed;
    f32x4*       out4 = (f32x4*)(outQ + (size_t)row0 * DIM);
    #pragma unroll
    for (int i = 0; i < 8; ++i) {
      int e = tid + i * 256;
      int r = e >> 5, c4 = e & 31;
      out4[e] = E4[fidx[r] * 32 + c4];
    }
  }
}

// -------- refine v2: coalesced full f32 rescan via embedT, f64 decision -----
__global__ __launch_bounds__(256) void refine2_kernel(
    const float* __restrict__ x, const float* __restrict__ embed,
    const float* __restrict__ embedT,
    const double* __restrict__ e2d, const float* __restrict__ e2f,
    float* __restrict__ outQ, float* __restrict__ outIdx,
    const int* __restrict__ cnt, const int* __restrict__ list)
{
  __shared__ f32x4 xst[DIM];                 // xst[k][r]: k-th dim of row r
  __shared__ float rb1[RPB][4], rb2[RPB][4];
  __shared__ int   ri1[RPB][4], ri2[RPB][4];
  __shared__ int   cand[RPB][2];

  const int t = threadIdx.x;
  const int l = t & 63, w = t >> 6;
  const int n = *cnt;
  float* xsf = (float*)xst;

  for (int base = blockIdx.x * RPB; base < n; base += RGRID * RPB) {
    const int nr = min(RPB, n - base);
    // stage rows (transposed: xst[k][r])
    #pragma unroll
    for (int i = 0; i < 2; ++i) {
      int idx = t + i * 256;
      int r = idx >> 7, k = idx & 127;
      float v = 0.f;
      if (r < nr) v = x[(size_t)list[base + r] * DIM + k];
      xsf[k * RPB + r] = v;
    }
    __syncthreads();

    // thread t owns codes 4t..4t+3; fully coalesced embedT stream
    f32x4 dot[RPB];
    #pragma unroll
    for (int r = 0; r < RPB; ++r) dot[r] = (f32x4){0.f, 0.f, 0.f, 0.f};
    const f32x4* eT4 = (const f32x4*)embedT;
    #pragma unroll 4
    for (int k = 0; k < DIM; ++k) {
      f32x4 e4  = eT4[k * 256 + t];
      f32x4 xk4 = xst[k];
      #pragma unroll
      for (int r = 0; r < RPB; ++r) {
        dot[r][0] = fmaf(xk4[r], e4[0], dot[r][0]);
        dot[r][1] = fmaf(xk4[r], e4[1], dot[r][1]);
        dot[r][2] = fmaf(xk4[r], e4[2], dot[r][2]);
        dot[r][3] = fmaf(xk4[r], e4[3], dot[r][3]);
      }
    }

    // per-thread top-2 over its 4 codes, then wave + block merges
    #pragma unroll
    for (int r = 0; r < RPB; ++r) {
      float b1 = 3.4e38f, b2 = 3.4e38f; int i1 = 0, i2 = 0;
      #pragma unroll
      for (int j = 0; j < 4; ++j) {
        int c = 4 * t + j;
        float sc = fmaf(-2.0f, dot[r][j], e2f[c]);
        bool better = (sc < b1);                 // ties keep lower index
        float lv = better ? b1 : sc;  int li = better ? i1 : c;
        if (better) { b1 = sc; i1 = c; }
        bool t2 = (lv < b2) || (lv == b2 && li < i2);
        if (t2) { b2 = lv; i2 = li; }
      }
      #pragma unroll
      for (int off = 1; off < 64; off <<= 1) {
        float o1 = __shfl_xor(b1, off, 64); int oi1 = __shfl_xor(i1, off, 64);
        float o2 = __shfl_xor(b2, off, 64); int oi2 = __shfl_xor(i2, off, 64);
        bool take = (o1 < b1) || (o1 == b1 && oi1 < i1);
        float n1 = take ? o1 : b1; int ni1 = take ? oi1 : i1;
        float lo = take ? b1 : o1; int loi = take ? i1 : oi1;
        float c2v = take ? o2 : b2; int c2i = take ? oi2 : i2;
        bool u2 = (c2v < lo) || (c2v == lo && c2i < loi);
        b1 = n1; i1 = ni1;
        b2 = u2 ? c2v : lo; i2 = u2 ? c2i : loi;
      }
      if (l == 0) { rb1[r][w] = b1; ri1[r][w] = i1; rb2[r][w] = b2; ri2[r][w] = i2; }
    }
    __syncthreads();

    if (t < RPB) {
      float v1 = rb1[t][0], v2 = rb2[t][0]; int j1 = ri1[t][0], j2 = ri2[t][0];
      #pragma unroll
      for (int ww = 1; ww < 4; ++ww) {
        float o1 = rb1[t][ww], o2 = rb2[t][ww]; int oi1 = ri1[t][ww], oi2 = ri2[t][ww];
        bool take = (o1 < v1) || (o1 == v1 && oi1 < j1);
        float n1 = take ? o1 : v1; int ni1 = take ? oi1 : j1;
        float lo = take ? v1 : o1; int loi = take ? j1 : oi1;
        float c2v = take ? o2 : v2; int c2i = take ? oi2 : j2;
        bool u2 = (c2v < lo) || (c2v == lo && c2i < loi);
        v1 = n1; j1 = ni1; v2 = u2 ? c2v : lo; j2 = u2 ? c2i : loi;
      }
      cand[t][0] = j1; cand[t][1] = j2;
    }
    __syncthreads();

    // f64 rescore of the two candidates: wave w handles row w
    if (w < nr) {
      int c1 = cand[w][0], c2 = cand[w][1];
      float xa = xsf[l * RPB + w], xb = xsf[(l + 64) * RPB + w];
      double p1 = (double)xa * (double)embed[(size_t)c1 * DIM + l]
                + (double)xb * (double)embed[(size_t)c1 * DIM + 64 + l];
      double p2 = (double)xa * (double)embed[(size_t)c2 * DIM + l]
                + (double)xb * (double)embed[(size_t)c2 * DIM + 64 + l];
      #pragma unroll
      for (int off = 1; off < 64; off <<= 1) {
        p1 += __shfl_xor(p1, off, 64);
        p2 += __shfl_xor(p2, off, 64);
      }
      double s1 = e2d[c1] - 2.0 * p1;
      double s2 = e2d[c2] - 2.0 * p2;
      int widx = ((s2 < s1) || (s2 == s1 && c2 < c1)) ? c2 : c1;
      int row = list[base + w];
      if (l == 0) outIdx[row] = (float)widx;
      outQ[(size_t)row * DIM + l]      = embed[(size_t)widx * DIM + l];
      outQ[(size_t)row * DIM + 64 + l] = embed[(size_t)widx * DIM + 64 + l];
    }
    __syncthreads();   // xst reused next trip
  }
}

extern "C" void kernel_launch(void* const* d_in, const int* in_sizes, int n_in,
                              void* d_out, int out_size, void* d_ws, size_t ws_size,
                              hipStream_t stream) {
  const float* x     = (const float*)d_in[0];
  const float* embed = (const float*)d_in[1];
  const int N = in_sizes[0] / DIM;             // 65536 rows

  float* out    = (float*)d_out;
  float* outQ   = out;                         // [N*128] quantize
  float* outIdx = out + (size_t)N * DIM;       // [N] indices as float

  char* ws = (char*)d_ws;
  double*   e2d  = (double*)  (ws);
  float*    e2f  = (float*)   (ws + 8192);
  _Float16* eh   = (_Float16*)(ws + 12288);
  float*    eT   = (float*)   (ws + 274432);
  int*      cnt  = (int*)     (ws + 798720);
  int*      list = (int*)     (ws + 798976);

  prep_kernel     <<<NCODES / 4, 256, 0, stream>>>(embed, e2d, e2f, eh, cnt);
  dim3 tg(DIM / 64, NCODES / 64);
  transpose_kernel<<<tg,         256, 0, stream>>>(embed, eT);
  pass1_kernel    <<<N / TILE_M, 256, 0, stream>>>(x, embed, eh, e2f, outQ, outIdx, cnt, list);
  refine2_kernel  <<<RGRID,      256, 0, stream>>>(x, embed, eT, e2d, e2f, outQ, outIdx, cnt, list);
}